// Round 5
// baseline (329.260 us; speedup 1.0000x reference)
//
#include <hip/hip_runtime.h>
#include <hip/hip_bf16.h>

// Problem constants (BertSelfAttention_979252544303)
#define SEQ   2048
#define BATCH 2
#define HID   1024
#define NHEAD 16
#define HDIM  64
#define BH    (BATCH * NHEAD)   // 32 flattened heads

using short4v  = __attribute__((ext_vector_type(4))) short;
using short8   = __attribute__((ext_vector_type(8))) short;
using floatx4  = __attribute__((ext_vector_type(4))) float;

#define LOG2E 1.44269504f
#define SCALE_LOG2E (0.125f * LOG2E)   // (1/sqrt(64)) * log2(e)

// float -> bf16 (RNE)
static __device__ __forceinline__ unsigned short f2bf(float f) {
    unsigned int u = __builtin_bit_cast(unsigned int, f);
    u += 0x7fffu + ((u >> 16) & 1u);
    return (unsigned short)(u >> 16);
}

// D = A(16x16 bf16) * B(16x16 bf16) + C  — per-wave MFMA, K=16
static __device__ __forceinline__ floatx4 mfma16x16x16(
    short4v a, short4v b, floatx4 c) {
#if __has_builtin(__builtin_amdgcn_mfma_f32_16x16x16bf16_1k)
    return __builtin_amdgcn_mfma_f32_16x16x16bf16_1k(a, b, c, 0, 0, 0);
#else
    floatx4 d;
    asm volatile("v_mfma_f32_16x16x16_bf16 %0, %1, %2, %3"
                 : "=v"(d) : "v"(a), "v"(b), "v"(c));
    return d;
#endif
}

#define GLD16(gp, lp)                                                        \
    __builtin_amdgcn_global_load_lds(                                        \
        (const __attribute__((address_space(1))) void*)(gp),                 \
        (__attribute__((address_space(3))) void*)(lp), 16, 0, 0)

// ---------------------------------------------------------------------------
// Prep 1: x fp32 [4096][1024] -> bf16 (straight). 1 float4 per thread.
// ---------------------------------------------------------------------------
__global__ __launch_bounds__(256) void convert_x(
    const float* __restrict__ x, unsigned short* __restrict__ xb)
{
    const int i = blockIdx.x * 256 + threadIdx.x;
    const float4 v = ((const float4*)x)[i];
    ushort4 o;
    o.x = f2bf(v.x); o.y = f2bf(v.y); o.z = f2bf(v.z); o.w = f2bf(v.w);
    ((ushort4*)xb)[i] = o;
}

// ---------------------------------------------------------------------------
// Prep 2: W fp32 [k][n] -> wt bf16 [n][k], tiled transpose. z selects Q/K/V.
// ---------------------------------------------------------------------------
__global__ __launch_bounds__(256) void transpose_w(
    const float* __restrict__ Wq, const float* __restrict__ Wk,
    const float* __restrict__ Wv, unsigned short* __restrict__ wt)
{
    const float* W = (blockIdx.z == 0) ? Wq : (blockIdx.z == 1) ? Wk : Wv;
    unsigned short* out = wt + (size_t)blockIdx.z * HID * HID;
    __shared__ float tile[32][33];
    const int tx = threadIdx.x & 31, ty = threadIdx.x >> 5;
    const int bx = blockIdx.x * 32, by = blockIdx.y * 32;
    #pragma unroll
    for (int j = 0; j < 4; ++j)
        tile[ty + j * 8][tx] = W[(size_t)(by + ty + j * 8) * HID + bx + tx];
    __syncthreads();
    #pragma unroll
    for (int j = 0; j < 4; ++j)
        out[(size_t)(bx + ty + j * 8) * HID + by + tx] = f2bf(tile[tx][ty + j * 8]);
}

// ---------------------------------------------------------------------------
// Kernel 1: fused QKV projection, bf16 MFMA, GLD16 ping-pong dbuf.
// z: 0=Q, 1=K (out [bh][s][d]) use direct scalar epilogue (d-contiguous,
// OK coalescing). z=2 (V, out [bh][d][s]) uses an LDS-bounce epilogue:
// the direct path was a 2-byte scatter at 4 KB stride (64 partial-line
// stores/wave); the bounce emits only full-128B-line dwordx4 stores.
// Shared LDS union: loop uses As/Bs dbuf (32 KB), epilogue reuses it as a
// 128x136 C tile (34.8 KB alloc; grid-bound at 3 blocks/CU regardless).
// ---------------------------------------------------------------------------
#define CTP 136   // C-tile pitch: 128 + 8 pad
__global__ __launch_bounds__(256) void qkv_mfma(
    const unsigned short* __restrict__ xb,
    const unsigned short* __restrict__ wt,
    const float* __restrict__ bq, const float* __restrict__ bk,
    const float* __restrict__ bv,
    unsigned short* __restrict__ ws_out)
{
    const int bn = blockIdx.x;   // 0..7
    const int bm = blockIdx.y;   // 0..31
    const int z  = blockIdx.z;   // 0..2
    const unsigned short* Bt = wt + (size_t)z * HID * HID;
    const float* bias = (z == 0) ? bq : (z == 1) ? bk : bv;
    unsigned short* out = ws_out + (size_t)z * (size_t)BH * SEQ * HDIM;

    const int t    = threadIdx.x;
    const int wave = t >> 6;
    const int lane = t & 63;
    const int l15  = lane & 15;
    const int quad = lane >> 4;
    const int wm   = (wave >> 1) * 64;
    const int wn   = (wave & 1) * 64;

    // union: [0,16384) = As dbuf + Bs dbuf (4x 4096 elems); epilogue C tile
    // needs 128*CTP = 17408 elems.
    __shared__ __align__(16) unsigned short smem[128 * CTP];
    #define ASB(buf) (smem + (buf) * 4096)
    #define BSB(buf) (smem + 8192 + (buf) * 4096)

    floatx4 acc[4][4];
    #pragma unroll
    for (int i = 0; i < 4; ++i)
        #pragma unroll
        for (int j = 0; j < 4; ++j)
            acc[i][j] = (floatx4){0.f, 0.f, 0.f, 0.f};

    const int lrow = lane >> 2;
    const int lcol = (lane & 3) * 8;

    #define QKV_STAGE(kt, buf)                                                  \
        do {                                                                    \
            _Pragma("unroll")                                                   \
            for (int ee = 0; ee < 2; ++ee) {                                    \
                const int e = wave * 2 + ee;                                    \
                const unsigned short* ga = xb +                                 \
                    (size_t)(bm * 128 + e * 16 + lrow) * HID + (kt) * 32 + lcol;\
                const unsigned short* gb = Bt +                                 \
                    (size_t)(bn * 128 + e * 16 + lrow) * HID + (kt) * 32 + lcol;\
                GLD16(ga, (char*)ASB(buf) + e * 1024);                          \
                GLD16(gb, (char*)BSB(buf) + e * 1024);                          \
            }                                                                   \
        } while (0)

    QKV_STAGE(0, 0);

    for (int kt = 0; kt < HID / 32; ++kt) {
        const int buf = kt & 1;
        __syncthreads();   // drains DMA for tile kt; syncs prev compute reads
        if (kt + 1 < HID / 32)
            QKV_STAGE(kt + 1, buf ^ 1);   // overlaps with compute below

        short8 af[4], bf[4];
        #pragma unroll
        for (int mt = 0; mt < 4; ++mt)
            af[mt] = *(const short8*)&ASB(buf)[(wm + mt * 16 + l15) * 32 + quad * 8];
        #pragma unroll
        for (int nt = 0; nt < 4; ++nt)
            bf[nt] = *(const short8*)&BSB(buf)[(wn + nt * 16 + l15) * 32 + quad * 8];
        #pragma unroll
        for (int mt = 0; mt < 4; ++mt)
            #pragma unroll
            for (int nt = 0; nt < 4; ++nt)
                acc[mt][nt] = __builtin_amdgcn_mfma_f32_16x16x32_bf16(
                    af[mt], bf[nt], acc[mt][nt], 0, 0, 0);
    }
    #undef QKV_STAGE

    if (z < 2) {
        #pragma unroll
        for (int nt = 0; nt < 4; ++nt) {
            const int n_g = bn * 128 + wn + nt * 16 + l15;
            const float bsv = bias[n_g];
            const int h = n_g >> 6;
            const int d = n_g & 63;
            #pragma unroll
            for (int mt = 0; mt < 4; ++mt) {
                #pragma unroll
                for (int r = 0; r < 4; ++r) {
                    const int m_g = bm * 128 + wm + mt * 16 + quad * 4 + r;
                    const int s  = m_g >> 1;
                    const int bb = m_g & 1;
                    out[((size_t)(bb * NHEAD + h) * SEQ + s) * HDIM + d] =
                        f2bf(acc[mt][nt][r] + bsv);
                }
            }
        }
    } else {
        // ---- V: LDS bounce -> coalesced [bh][d][s] stores ----
        __syncthreads();   // all frag reads from As/Bs complete before reuse
        #pragma unroll
        for (int nt = 0; nt < 4; ++nt) {
            const int n_l = wn + nt * 16 + l15;
            const float bsv = bias[bn * 128 + n_l];
            #pragma unroll
            for (int mt = 0; mt < 4; ++mt) {
                #pragma unroll
                for (int r = 0; r < 4; ++r) {
                    const int m_l = wm + mt * 16 + quad * 4 + r;
                    // m -> (s_l, bb): s interleaved with batch (BATCH==2)
                    smem[n_l * CTP + (m_l & 1) * 64 + (m_l >> 1)] =
                        f2bf(acc[mt][nt][r] + bsv);
                }
            }
        }
        __syncthreads();
        // read back: thread t owns row (n_l = t>>1, bb = t&1) = 64 s * 2B
        const int n_l = t >> 1;
        const int b2  = t & 1;
        const int n_g = bn * 128 + n_l;
        const int h   = n_g >> 6;
        const int d   = n_g & 63;
        const unsigned short* src = smem + n_l * CTP + b2 * 64;
        unsigned short* dst =
            out + ((size_t)(b2 * NHEAD + h) * HDIM + d) * SEQ + bm * 64;
        #pragma unroll
        for (int c = 0; c < 8; ++c)    // 8 x 16B = 128 B (one full line set)
            *(uint4*)(dst + c * 8) = *(const uint4*)(src + c * 8);
    }
}
#undef CTP

// ---------------------------------------------------------------------------
// Kernel 2: flash attention v13 = v12 team-split occupancy fix, register-lean.
//   Round-4 bench died at the container level (no counters). v12 audit found
//   no deadlock (all barriers wave-uniform) and no OOB, but one real risk:
//   __launch_bounds__(512,8) forces VGPR<=64 while v12's live state (Of 16 +
//   Qf 8 + kreg/vreg 16 + mreg 16 + mnext 16 + addr) was ~76 -> forced spill.
//   v13 drops the mask double-buffer: at 8 waves/SIMD (the point of this
//   kernel) TLP covers the mask L2 latency, so mld[] for the CURRENT tile is
//   loaded right after the first barrier (use distance ~200+ cy). Numerics
//   identical to v9/v11: exp2f(fmaf(c, SCALE_LOG2E, m*LOG2E)).
//   Structure: 512 threads, 8 waves; team = wave>>2. Team 0 = even 64-key
//   tiles, team 1 = odd tiles, per-team K/V LDS pairs (32 KB/block), per-team
//   K/V register prefetch. Waves/CU 16 -> 32 at 4 blocks/CU (LDS 128<=160KB).
//   Partial (Of, lst) merged across teams via LDS; fixed-shift softmax (no
//   running max) makes the merge a plain add. f32 sum regrouping only.
//   LDS tile layout proven in v9/v11: 128 B rows, XOR swizzle
//   byte = row*128 + (col ^ ((row&7)<<4)), both staging writes and reads.
// q,kp: [bh][s][d] bf16; vt: [bh][d][s] bf16; mask: [B][1][S][S] fp32.
// ---------------------------------------------------------------------------
__global__ __launch_bounds__(512, 8) void attn_v13(
    const unsigned short* __restrict__ q,
    const unsigned short* __restrict__ kp,
    const unsigned short* __restrict__ vt,
    const float* __restrict__ mask,
    float* __restrict__ out)
{
    const int qb   = blockIdx.x;   // 0..31 query tile (64 rows)
    const int n    = blockIdx.y;   // 0..31 flattened head
    const int t    = threadIdx.x;  // 0..511
    const int wave = t >> 6;       // 0..7
    const int team = wave >> 2;    // 0: even kt tiles, 1: odd kt tiles
    const int wv   = wave & 3;     // q-row group (rows wv*16..wv*16+15)
    const int lane = t & 63;
    const int l15  = lane & 15;
    const int quad = lane >> 4;
    const int bb   = n >> 4;       // batch
    const int hh   = n & 15;       // head

    // per-team 64x64 bf16 tiles, 128 B rows, XOR-swizzled
    __shared__ __align__(16) unsigned short Ks[2][64 * 64];
    __shared__ __align__(16) unsigned short Vs[2][64 * 64];
    char* const KsB = (char*)Ks[team];
    char* const VsB = (char*)Vs[team];

    // ---- Q fragments straight from global (one-time) ----
    const unsigned short* qbase = q + ((size_t)n * SEQ + qb * 64) * HDIM;
    short8 Qf[2];
    #pragma unroll
    for (int ks = 0; ks < 2; ++ks)
        Qf[ks] = *(const short8*)(qbase +
            (size_t)(wv * 16 + l15) * HDIM + ks * 32 + quad * 8);

    floatx4 Of[4];
    #pragma unroll
    for (int nt = 0; nt < 4; ++nt) Of[nt] = (floatx4){0.f, 0.f, 0.f, 0.f};
    float lst = 0.0f;

    const unsigned short* kbase = kp + (size_t)n * SEQ * HDIM;
    const unsigned short* vbase = vt + (size_t)n * HDIM * SEQ;
    const float* mrow = mask + ((size_t)bb * SEQ + qb * 64 + wv * 16 + l15) * SEQ;

    // per-thread staging addresses within the team's 256 threads
    const int t256 = t & 255;
    const int c0 = t256,       r0 = c0 >> 3, o0 = (c0 & 7) * 8;
    const int c1 = t256 + 256, r1 = c1 >> 3, o1 = (c1 & 7) * 8;
    // swizzled LDS byte destinations for the staging writes
    const int sw0 = r0 * 128 + ((o0 * 2) ^ ((r0 & 7) << 4));
    const int sw1 = r1 * 128 + ((o1 * 2) ^ ((r1 & 7) << 4));
    // read-side swizzle term (row & 7 == l15 & 7 for all fragment reads)
    const int rsw = (l15 & 7) << 4;

    uint4 kreg0, kreg1, vreg0, vreg1;
    {   // prefetch this team's first tile (tile index = team)
        const unsigned short* kb = kbase + (size_t)(team * 64) * HDIM;
        const unsigned short* vb = vbase + team * 64;
        kreg0 = *(const uint4*)(kb + (size_t)r0 * HDIM + o0);
        kreg1 = *(const uint4*)(kb + (size_t)r1 * HDIM + o1);
        vreg0 = *(const uint4*)(vb + (size_t)r0 * SEQ + o0);
        vreg1 = *(const uint4*)(vb + (size_t)r1 * SEQ + o1);
    }

    for (int it = 0; it < SEQ / 128; ++it) {
        const int tile = it * 2 + team;
        __syncthreads();   // previous tiles fully consumed (both teams)

        // mask for THIS tile: issue early; consumed after LDS stores + sync +
        // ds_reads + 2 MFMAs (~200+ cy) and covered by 8-wave/SIMD TLP.
        float4 mld[4];
        #pragma unroll
        for (int mt = 0; mt < 4; ++mt)
            mld[mt] = *(const float4*)(mrow + tile * 64 + mt * 16 + quad * 4);

        *(uint4*)(KsB + sw0) = kreg0;
        *(uint4*)(KsB + sw1) = kreg1;
        *(uint4*)(VsB + sw0) = vreg0;
        *(uint4*)(VsB + sw1) = vreg1;
        __syncthreads();   // tiles visible

        if (it + 1 < SEQ / 128) {   // prefetch this team's next tile
            const int nt2 = tile + 2;
            const unsigned short* kb = kbase + (size_t)(nt2 * 64) * HDIM;
            const unsigned short* vb = vbase + nt2 * 64;
            kreg0 = *(const uint4*)(kb + (size_t)r0 * HDIM + o0);
            kreg1 = *(const uint4*)(kb + (size_t)r1 * HDIM + o1);
            vreg0 = *(const uint4*)(vb + (size_t)r0 * SEQ + o0);
            vreg1 = *(const uint4*)(vb + (size_t)r1 * SEQ + o1);
        }

        // per 16-key subtile: S^T MFMA -> softmax -> in-register P -> PV
        #pragma unroll
        for (int mt = 0; mt < 4; ++mt) {
            floatx4 c = (floatx4){0.f, 0.f, 0.f, 0.f};
            #pragma unroll
            for (int ks = 0; ks < 2; ++ks) {
                short8 a = *(const short8*)(KsB + (mt * 16 + l15) * 128 +
                                            ((ks * 64 + quad * 16) ^ rsw));
                c = __builtin_amdgcn_mfma_f32_16x16x32_bf16(a, Qf[ks], c, 0, 0, 0);
            }

            const float4 mv = mld[mt];
            const float pv0 = exp2f(fmaf(c[0], SCALE_LOG2E, mv.x * LOG2E));
            const float pv1 = exp2f(fmaf(c[1], SCALE_LOG2E, mv.y * LOG2E));
            const float pv2 = exp2f(fmaf(c[2], SCALE_LOG2E, mv.z * LOG2E));
            const float pv3 = exp2f(fmaf(c[3], SCALE_LOG2E, mv.w * LOG2E));
            lst += (pv0 + pv1) + (pv2 + pv3);

            short4v Af;
            Af[0] = (short)f2bf(pv0);
            Af[1] = (short)f2bf(pv1);
            Af[2] = (short)f2bf(pv2);
            Af[3] = (short)f2bf(pv3);

            #pragma unroll
            for (int nt = 0; nt < 4; ++nt) {
                short4v Bf = *(const short4v*)(VsB + (nt * 16 + l15) * 128 +
                                               ((mt * 32 + quad * 8) ^ rsw));
                Of[nt] = mfma16x16x16(Af, Bf, Of[nt]);
            }
        }
    }

    // ---- per-wave quad reduction of lst (full row sums for own keys) ----
    lst += __shfl_xor(lst, 16);
    lst += __shfl_xor(lst, 32);

    // ---- cross-team merge via LDS (fixed-shift softmax: merge = add) ----
    __syncthreads();   // K/V buffers no longer needed
    float* const Obuf = (float*)&Ks[0][0];            // 256 rows * 16 f32 = 16 KB
    float* const Lbuf = (float*)&Vs[0][0];            // 256 f32 = 1 KB
    if (team == 1) {
        float* dst = Obuf + (size_t)(wv * 64 + lane) * 16;
        #pragma unroll
        for (int nt = 0; nt < 4; ++nt)
            *(floatx4*)(dst + nt * 4) = Of[nt];
        Lbuf[wv * 64 + lane] = lst;
    }
    __syncthreads();
    if (team == 0) {
        const float* src = Obuf + (size_t)(wv * 64 + lane) * 16;
        #pragma unroll
        for (int nt = 0; nt < 4; ++nt)
            Of[nt] += *(const floatx4*)(src + nt * 4);
        lst += Lbuf[wv * 64 + lane];

        // normalize + store
        #pragma unroll
        for (int r = 0; r < 4; ++r) {
            const float lrow = __shfl(lst, quad * 4 + r);   // row q = quad*4+r
            const float inv  = 1.0f / lrow;
            const int s = qb * 64 + wv * 16 + quad * 4 + r;
            float* orow = out + ((size_t)s * BATCH + bb) * HID + hh * 64;
            #pragma unroll
            for (int nt = 0; nt < 4; ++nt)
                orow[nt * 16 + l15] = Of[nt][r] * inv;
        }
    }
}

// ---------------------------------------------------------------------------
extern "C" void kernel_launch(void* const* d_in, const int* in_sizes, int n_in,
                              void* d_out, int out_size, void* d_ws, size_t ws_size,
                              hipStream_t stream) {
    const float* x    = (const float*)d_in[0];
    const float* mask = (const float*)d_in[1];
    const float* Wq   = (const float*)d_in[2];
    const float* bq   = (const float*)d_in[3];
    const float* Wk   = (const float*)d_in[4];
    const float* bk   = (const float*)d_in[5];
    const float* Wv   = (const float*)d_in[6];
    const float* bv   = (const float*)d_in[7];
    float* out = (float*)d_out;

    const size_t per = (size_t)BH * SEQ * HDIM;   // 4,194,304 elems (8 MB bf16)
    unsigned short* qw = (unsigned short*)d_ws;   // 8 MB
    unsigned short* kw = qw + per;                // 8 MB
    unsigned short* vw = kw + per;                // 8 MB (V transposed [bh][d][s])
    unsigned short* xb = vw + per;                // 8 MB (x bf16)
    unsigned short* wt = xb + per;                // 6 MB (3x W^T bf16)

    convert_x<<<dim3(SEQ * BATCH * HID / 4 / 256), dim3(256), 0, stream>>>(x, xb);
    transpose_w<<<dim3(32, 32, 3), dim3(256), 0, stream>>>(Wq, Wk, Wv, wt);

    qkv_mfma<<<dim3(HID / 128, SEQ * BATCH / 128, 3), dim3(256), 0, stream>>>(
        xb, wt, bq, bk, bv, qw);

    attn_v13<<<dim3(SEQ / 64, BH), dim3(512), 0, stream>>>(qw, kw, vw, mask, out);
}

// Round 6
// 242.839 us; speedup vs baseline: 1.3559x; 1.3559x over previous
//
#include <hip/hip_runtime.h>
#include <hip/hip_bf16.h>

// Problem constants (BertSelfAttention_979252544303)
#define SEQ   2048
#define BATCH 2
#define HID   1024
#define NHEAD 16
#define HDIM  64
#define BH    (BATCH * NHEAD)   // 32 flattened heads

using short4v  = __attribute__((ext_vector_type(4))) short;
using short8   = __attribute__((ext_vector_type(8))) short;
using floatx4  = __attribute__((ext_vector_type(4))) float;

#define LOG2E 1.44269504f
#define SCALE_LOG2E (0.125f * LOG2E)   // (1/sqrt(64)) * log2(e)

// float -> bf16 (RNE)
static __device__ __forceinline__ unsigned short f2bf(float f) {
    unsigned int u = __builtin_bit_cast(unsigned int, f);
    u += 0x7fffu + ((u >> 16) & 1u);
    return (unsigned short)(u >> 16);
}

// D = A(16x16 bf16) * B(16x16 bf16) + C  — per-wave MFMA, K=16
static __device__ __forceinline__ floatx4 mfma16x16x16(
    short4v a, short4v b, floatx4 c) {
#if __has_builtin(__builtin_amdgcn_mfma_f32_16x16x16bf16_1k)
    return __builtin_amdgcn_mfma_f32_16x16x16bf16_1k(a, b, c, 0, 0, 0);
#else
    floatx4 d;
    asm volatile("v_mfma_f32_16x16x16_bf16 %0, %1, %2, %3"
                 : "=v"(d) : "v"(a), "v"(b), "v"(c));
    return d;
#endif
}

#define GLD16(gp, lp)                                                        \
    __builtin_amdgcn_global_load_lds(                                        \
        (const __attribute__((address_space(1))) void*)(gp),                 \
        (__attribute__((address_space(3))) void*)(lp), 16, 0, 0)

// ---------------------------------------------------------------------------
// Prep 1: x fp32 [4096][1024] -> bf16 (straight). 1 float4 per thread.
// ---------------------------------------------------------------------------
__global__ __launch_bounds__(256) void convert_x(
    const float* __restrict__ x, unsigned short* __restrict__ xb)
{
    const int i = blockIdx.x * 256 + threadIdx.x;
    const float4 v = ((const float4*)x)[i];
    ushort4 o;
    o.x = f2bf(v.x); o.y = f2bf(v.y); o.z = f2bf(v.z); o.w = f2bf(v.w);
    ((ushort4*)xb)[i] = o;
}

// ---------------------------------------------------------------------------
// Prep 2: W fp32 [k][n] -> wt bf16 [n][k], tiled transpose. z selects Q/K/V.
// ---------------------------------------------------------------------------
__global__ __launch_bounds__(256) void transpose_w(
    const float* __restrict__ Wq, const float* __restrict__ Wk,
    const float* __restrict__ Wv, unsigned short* __restrict__ wt)
{
    const float* W = (blockIdx.z == 0) ? Wq : (blockIdx.z == 1) ? Wk : Wv;
    unsigned short* out = wt + (size_t)blockIdx.z * HID * HID;
    __shared__ float tile[32][33];
    const int tx = threadIdx.x & 31, ty = threadIdx.x >> 5;
    const int bx = blockIdx.x * 32, by = blockIdx.y * 32;
    #pragma unroll
    for (int j = 0; j < 4; ++j)
        tile[ty + j * 8][tx] = W[(size_t)(by + ty + j * 8) * HID + bx + tx];
    __syncthreads();
    #pragma unroll
    for (int j = 0; j < 4; ++j)
        out[(size_t)(bx + ty + j * 8) * HID + by + tx] = f2bf(tile[tx][ty + j * 8]);
}

// ---------------------------------------------------------------------------
// Kernel 1: fused QKV projection, bf16 MFMA, GLD16 ping-pong dbuf.
// z: 0=Q, 1=K (out [bh][s][d]) use direct scalar epilogue (d-contiguous,
// OK coalescing). z=2 (V, out [bh][d][s]) uses an LDS-bounce epilogue:
// the direct path was a 2-byte scatter at 4 KB stride (64 partial-line
// stores/wave); the bounce emits only full-128B-line dwordx4 stores.
// Shared LDS union: loop uses As/Bs dbuf (32 KB), epilogue reuses it as a
// 128x136 C tile (34.8 KB alloc; grid-bound at 3 blocks/CU regardless).
// ---------------------------------------------------------------------------
#define CTP 136   // C-tile pitch: 128 + 8 pad
__global__ __launch_bounds__(256) void qkv_mfma(
    const unsigned short* __restrict__ xb,
    const unsigned short* __restrict__ wt,
    const float* __restrict__ bq, const float* __restrict__ bk,
    const float* __restrict__ bv,
    unsigned short* __restrict__ ws_out)
{
    const int bn = blockIdx.x;   // 0..7
    const int bm = blockIdx.y;   // 0..31
    const int z  = blockIdx.z;   // 0..2
    const unsigned short* Bt = wt + (size_t)z * HID * HID;
    const float* bias = (z == 0) ? bq : (z == 1) ? bk : bv;
    unsigned short* out = ws_out + (size_t)z * (size_t)BH * SEQ * HDIM;

    const int t    = threadIdx.x;
    const int wave = t >> 6;
    const int lane = t & 63;
    const int l15  = lane & 15;
    const int quad = lane >> 4;
    const int wm   = (wave >> 1) * 64;
    const int wn   = (wave & 1) * 64;

    // union: [0,16384) = As dbuf + Bs dbuf (4x 4096 elems); epilogue C tile
    // needs 128*CTP = 17408 elems.
    __shared__ __align__(16) unsigned short smem[128 * CTP];
    #define ASB(buf) (smem + (buf) * 4096)
    #define BSB(buf) (smem + 8192 + (buf) * 4096)

    floatx4 acc[4][4];
    #pragma unroll
    for (int i = 0; i < 4; ++i)
        #pragma unroll
        for (int j = 0; j < 4; ++j)
            acc[i][j] = (floatx4){0.f, 0.f, 0.f, 0.f};

    const int lrow = lane >> 2;
    const int lcol = (lane & 3) * 8;

    #define QKV_STAGE(kt, buf)                                                  \
        do {                                                                    \
            _Pragma("unroll")                                                   \
            for (int ee = 0; ee < 2; ++ee) {                                    \
                const int e = wave * 2 + ee;                                    \
                const unsigned short* ga = xb +                                 \
                    (size_t)(bm * 128 + e * 16 + lrow) * HID + (kt) * 32 + lcol;\
                const unsigned short* gb = Bt +                                 \
                    (size_t)(bn * 128 + e * 16 + lrow) * HID + (kt) * 32 + lcol;\
                GLD16(ga, (char*)ASB(buf) + e * 1024);                          \
                GLD16(gb, (char*)BSB(buf) + e * 1024);                          \
            }                                                                   \
        } while (0)

    QKV_STAGE(0, 0);

    for (int kt = 0; kt < HID / 32; ++kt) {
        const int buf = kt & 1;
        __syncthreads();   // drains DMA for tile kt; syncs prev compute reads
        if (kt + 1 < HID / 32)
            QKV_STAGE(kt + 1, buf ^ 1);   // overlaps with compute below

        short8 af[4], bf[4];
        #pragma unroll
        for (int mt = 0; mt < 4; ++mt)
            af[mt] = *(const short8*)&ASB(buf)[(wm + mt * 16 + l15) * 32 + quad * 8];
        #pragma unroll
        for (int nt = 0; nt < 4; ++nt)
            bf[nt] = *(const short8*)&BSB(buf)[(wn + nt * 16 + l15) * 32 + quad * 8];
        #pragma unroll
        for (int mt = 0; mt < 4; ++mt)
            #pragma unroll
            for (int nt = 0; nt < 4; ++nt)
                acc[mt][nt] = __builtin_amdgcn_mfma_f32_16x16x32_bf16(
                    af[mt], bf[nt], acc[mt][nt], 0, 0, 0);
    }
    #undef QKV_STAGE

    if (z < 2) {
        #pragma unroll
        for (int nt = 0; nt < 4; ++nt) {
            const int n_g = bn * 128 + wn + nt * 16 + l15;
            const float bsv = bias[n_g];
            const int h = n_g >> 6;
            const int d = n_g & 63;
            #pragma unroll
            for (int mt = 0; mt < 4; ++mt) {
                #pragma unroll
                for (int r = 0; r < 4; ++r) {
                    const int m_g = bm * 128 + wm + mt * 16 + quad * 4 + r;
                    const int s  = m_g >> 1;
                    const int bb = m_g & 1;
                    out[((size_t)(bb * NHEAD + h) * SEQ + s) * HDIM + d] =
                        f2bf(acc[mt][nt][r] + bsv);
                }
            }
        }
    } else {
        // ---- V: LDS bounce -> coalesced [bh][d][s] stores ----
        __syncthreads();   // all frag reads from As/Bs complete before reuse
        #pragma unroll
        for (int nt = 0; nt < 4; ++nt) {
            const int n_l = wn + nt * 16 + l15;
            const float bsv = bias[bn * 128 + n_l];
            #pragma unroll
            for (int mt = 0; mt < 4; ++mt) {
                #pragma unroll
                for (int r = 0; r < 4; ++r) {
                    const int m_l = wm + mt * 16 + quad * 4 + r;
                    // m -> (s_l, bb): s interleaved with batch (BATCH==2)
                    smem[n_l * CTP + (m_l & 1) * 64 + (m_l >> 1)] =
                        f2bf(acc[mt][nt][r] + bsv);
                }
            }
        }
        __syncthreads();
        // read back: thread t owns row (n_l = t>>1, bb = t&1) = 64 s * 2B
        const int n_l = t >> 1;
        const int b2  = t & 1;
        const int n_g = bn * 128 + n_l;
        const int h   = n_g >> 6;
        const int d   = n_g & 63;
        const unsigned short* src = smem + n_l * CTP + b2 * 64;
        unsigned short* dst =
            out + ((size_t)(b2 * NHEAD + h) * HDIM + d) * SEQ + bm * 64;
        #pragma unroll
        for (int c = 0; c < 8; ++c)    // 8 x 16B = 128 B (one full line set)
            *(uint4*)(dst + c * 8) = *(const uint4*)(src + c * 8);
    }
}
#undef CTP

// ---------------------------------------------------------------------------
// Kernel 2: flash attention v14 — team split, register-lean (v13 post-mortem).
//   v13 FAILED by spilling: __launch_bounds__(512,8) forced a 64-reg unified
//   budget; gfx950 split it ~32 arch VGPR + 32 AGPR (MFMA accumulators), so
//   ~60 live values squeezed into 32 arch regs -> WRITE_SIZE 16->147 MB
//   (scratch), attn 196 µs. v14 fixes by REDUCING DEMAND, not forcing:
//   - KVBLK=32 per team (teams interleave 32-key tiles): prefetch regs 16->8,
//     mask transient 16->8. Live state ~55-60.
//   - __launch_bounds__(512) with NO min-waves: compiler allocates freely
//     (no spill possible); at ~60-64 VGPR it reaches 7-8 waves/EU naturally.
//   Structure: 512 thr, 8 waves; team=wave>>2 (0=even 32-key tiles, 1=odd),
//   wv=wave&3 owns q-rows wv*16..+15. Per-team LDS: K 32x64 bf16 (128B rows,
//   XOR swizzle byte^=((row&7)<<4), proven v9-v11) + V 64x32 bf16 (64B rows,
//   16B-unit swizzle byte^=(((row>>1)&3)<<4): write 2-way free, b64 frag
//   read 2-way free, 16B units intact for uint4 writes). 8 KB/team,
//   16 KB tiles + 1 KB merge Lbuf = 17.4 KB/block.
//   Merge: fixed-shift softmax (no running max) -> partial (Of,lst) merge is
//   a plain add via LDS; team 0 normalizes and stores. f32 regroup only.
// q,kp: [bh][s][d] bf16; vt: [bh][d][s] bf16; mask: [B][1][S][S] fp32.
// ---------------------------------------------------------------------------
__global__ __launch_bounds__(512) void attn_v14(
    const unsigned short* __restrict__ q,
    const unsigned short* __restrict__ kp,
    const unsigned short* __restrict__ vt,
    const float* __restrict__ mask,
    float* __restrict__ out)
{
    const int qb   = blockIdx.x;   // 0..31 query tile (64 rows)
    const int n    = blockIdx.y;   // 0..31 flattened head
    const int t    = threadIdx.x;  // 0..511
    const int wave = t >> 6;       // 0..7
    const int team = wave >> 2;    // 0: even 32-key tiles, 1: odd
    const int wv   = wave & 3;     // q-row group (rows wv*16..wv*16+15)
    const int lane = t & 63;
    const int l15  = lane & 15;
    const int quad = lane >> 4;
    const int bb   = n >> 4;       // batch
    const int hh   = n & 15;       // head

    // [0,8192): team0 K(4KB)+V(4KB); [8192,16384): team1. Epilogue reuses
    // [0,16384) as Obuf (f32) and [16384,17408) as Lbuf.
    __shared__ __align__(16) char smem[17408];
    char* const KsB = smem + team * 8192;          // 32x64 bf16, 128 B rows
    char* const VsB = smem + team * 8192 + 4096;   // 64x32 bf16, 64 B rows

    // ---- Q fragments straight from global (one-time) ----
    const unsigned short* qbase = q + ((size_t)n * SEQ + qb * 64) * HDIM;
    short8 Qf[2];
    #pragma unroll
    for (int ks = 0; ks < 2; ++ks)
        Qf[ks] = *(const short8*)(qbase +
            (size_t)(wv * 16 + l15) * HDIM + ks * 32 + quad * 8);

    floatx4 Of[4];
    #pragma unroll
    for (int nt = 0; nt < 4; ++nt) Of[nt] = (floatx4){0.f, 0.f, 0.f, 0.f};
    float lst = 0.0f;

    const unsigned short* kbase = kp + (size_t)n * SEQ * HDIM;
    const unsigned short* vbase = vt + (size_t)n * HDIM * SEQ;
    const float* mrow = mask + ((size_t)bb * SEQ + qb * 64 + wv * 16 + l15) * SEQ;

    // staging addresses within the team's 256 threads
    const int t256 = t & 255;
    const int kr = t256 >> 3, ko = (t256 & 7) * 8;        // K: 32 rows x 8 chunks
    const int ksw = kr * 128 + ((ko * 2) ^ ((kr & 7) << 4));
    const int vr = t256 >> 2, vo = (t256 & 3) * 8;        // V: 64 rows x 4 chunks
    const int vsw = vr * 64 + ((vo * 2) ^ (((vr >> 1) & 3) << 4));
    // read-side swizzle terms (lane-constant)
    const int rswK = (l15 & 7) << 4;
    const int rswV = ((l15 >> 1) & 3) << 4;

    uint4 kreg, vreg;
    {   // prefetch this team's first tile (tile index = team)
        kreg = *(const uint4*)(kbase + (size_t)(team * 32 + kr) * HDIM + ko);
        vreg = *(const uint4*)(vbase + (size_t)vr * SEQ + team * 32 + vo);
    }

    for (int it = 0; it < SEQ / 64; ++it) {   // 32 iters; team tile = it*2+team
        const int tile = it * 2 + team;
        __syncthreads();   // previous tiles fully consumed (both teams)

        // mask for THIS tile (8 floats); issued early, covered by TLP + the
        // staging/sync/QK^T distance before first use.
        float4 mld[2];
        #pragma unroll
        for (int mt = 0; mt < 2; ++mt)
            mld[mt] = *(const float4*)(mrow + tile * 32 + mt * 16 + quad * 4);

        *(uint4*)(KsB + ksw) = kreg;
        *(uint4*)(VsB + vsw) = vreg;
        __syncthreads();   // tiles visible

        if (it + 1 < SEQ / 64) {   // prefetch this team's next tile
            const int nt2 = tile + 2;
            kreg = *(const uint4*)(kbase + (size_t)(nt2 * 32 + kr) * HDIM + ko);
            vreg = *(const uint4*)(vbase + (size_t)vr * SEQ + nt2 * 32 + vo);
        }

        // per 16-key subtile: S^T MFMA -> softmax -> in-register P -> PV
        #pragma unroll
        for (int mt = 0; mt < 2; ++mt) {
            floatx4 c = (floatx4){0.f, 0.f, 0.f, 0.f};
            #pragma unroll
            for (int ks = 0; ks < 2; ++ks) {
                short8 a = *(const short8*)(KsB + (mt * 16 + l15) * 128 +
                                            ((ks * 64 + quad * 16) ^ rswK));
                c = __builtin_amdgcn_mfma_f32_16x16x32_bf16(a, Qf[ks], c, 0, 0, 0);
            }

            const float4 mv = mld[mt];
            const float pv0 = exp2f(fmaf(c[0], SCALE_LOG2E, mv.x * LOG2E));
            const float pv1 = exp2f(fmaf(c[1], SCALE_LOG2E, mv.y * LOG2E));
            const float pv2 = exp2f(fmaf(c[2], SCALE_LOG2E, mv.z * LOG2E));
            const float pv3 = exp2f(fmaf(c[3], SCALE_LOG2E, mv.w * LOG2E));
            lst += (pv0 + pv1) + (pv2 + pv3);

            short4v Af;
            Af[0] = (short)f2bf(pv0);
            Af[1] = (short)f2bf(pv1);
            Af[2] = (short)f2bf(pv2);
            Af[3] = (short)f2bf(pv3);

            #pragma unroll
            for (int nt = 0; nt < 4; ++nt) {
                short4v Bf = *(const short4v*)(VsB + (nt * 16 + l15) * 64 +
                                               ((mt * 32 + quad * 8) ^ rswV));
                Of[nt] = mfma16x16x16(Af, Bf, Of[nt]);
            }
        }
    }

    // ---- per-wave quad reduction of lst (full row sums for own keys) ----
    lst += __shfl_xor(lst, 16);
    lst += __shfl_xor(lst, 32);

    // ---- cross-team merge via LDS (fixed-shift softmax: merge = add) ----
    __syncthreads();   // K/V buffers no longer needed
    float* const Obuf = (float*)smem;              // 256 rows * 16 f32 = 16 KB
    float* const Lbuf = (float*)(smem + 16384);    // 256 f32 = 1 KB
    if (team == 1) {
        float* dst = Obuf + (size_t)(wv * 64 + lane) * 16;
        #pragma unroll
        for (int nt = 0; nt < 4; ++nt)
            *(floatx4*)(dst + nt * 4) = Of[nt];
        Lbuf[wv * 64 + lane] = lst;
    }
    __syncthreads();
    if (team == 0) {
        const float* src = Obuf + (size_t)(wv * 64 + lane) * 16;
        #pragma unroll
        for (int nt = 0; nt < 4; ++nt)
            Of[nt] += *(const floatx4*)(src + nt * 4);
        lst += Lbuf[wv * 64 + lane];

        // normalize + store
        #pragma unroll
        for (int r = 0; r < 4; ++r) {
            const float lrow = __shfl(lst, quad * 4 + r);   // row q = quad*4+r
            const float inv  = 1.0f / lrow;
            const int s = qb * 64 + wv * 16 + quad * 4 + r;
            float* orow = out + ((size_t)s * BATCH + bb) * HID + hh * 64;
            #pragma unroll
            for (int nt = 0; nt < 4; ++nt)
                orow[nt * 16 + l15] = Of[nt][r] * inv;
        }
    }
}

// ---------------------------------------------------------------------------
extern "C" void kernel_launch(void* const* d_in, const int* in_sizes, int n_in,
                              void* d_out, int out_size, void* d_ws, size_t ws_size,
                              hipStream_t stream) {
    const float* x    = (const float*)d_in[0];
    const float* mask = (const float*)d_in[1];
    const float* Wq   = (const float*)d_in[2];
    const float* bq   = (const float*)d_in[3];
    const float* Wk   = (const float*)d_in[4];
    const float* bk   = (const float*)d_in[5];
    const float* Wv   = (const float*)d_in[6];
    const float* bv   = (const float*)d_in[7];
    float* out = (float*)d_out;

    const size_t per = (size_t)BH * SEQ * HDIM;   // 4,194,304 elems (8 MB bf16)
    unsigned short* qw = (unsigned short*)d_ws;   // 8 MB
    unsigned short* kw = qw + per;                // 8 MB
    unsigned short* vw = kw + per;                // 8 MB (V transposed [bh][d][s])
    unsigned short* xb = vw + per;                // 8 MB (x bf16)
    unsigned short* wt = xb + per;                // 6 MB (3x W^T bf16)

    convert_x<<<dim3(SEQ * BATCH * HID / 4 / 256), dim3(256), 0, stream>>>(x, xb);
    transpose_w<<<dim3(32, 32, 3), dim3(256), 0, stream>>>(Wq, Wk, Wv, wt);

    qkv_mfma<<<dim3(HID / 128, SEQ * BATCH / 128, 3), dim3(256), 0, stream>>>(
        xb, wt, bq, bk, bv, qw);

    attn_v14<<<dim3(SEQ / 64, BH), dim3(512), 0, stream>>>(qw, kw, vw, mask, out);
}

// Round 7
// 236.618 us; speedup vs baseline: 1.3915x; 1.0263x over previous
//
#include <hip/hip_runtime.h>
#include <hip/hip_bf16.h>

// Problem constants (BertSelfAttention_979252544303)
#define SEQ   2048
#define BATCH 2
#define HID   1024
#define NHEAD 16
#define HDIM  64
#define BH    (BATCH * NHEAD)   // 32 flattened heads

using short4v  = __attribute__((ext_vector_type(4))) short;
using short8   = __attribute__((ext_vector_type(8))) short;
using floatx4  = __attribute__((ext_vector_type(4))) float;

#define LOG2E 1.44269504f
#define SCALE_LOG2E (0.125f * LOG2E)   // (1/sqrt(64)) * log2(e)

// float -> bf16 (RNE)
static __device__ __forceinline__ unsigned short f2bf(float f) {
    unsigned int u = __builtin_bit_cast(unsigned int, f);
    u += 0x7fffu + ((u >> 16) & 1u);
    return (unsigned short)(u >> 16);
}

static __device__ __forceinline__ float4 mul4(float4 a, float s) {
    return make_float4(a.x * s, a.y * s, a.z * s, a.w * s);
}

// D = A(16x16 bf16) * B(16x16 bf16) + C  — per-wave MFMA, K=16
static __device__ __forceinline__ floatx4 mfma16x16x16(
    short4v a, short4v b, floatx4 c) {
#if __has_builtin(__builtin_amdgcn_mfma_f32_16x16x16bf16_1k)
    return __builtin_amdgcn_mfma_f32_16x16x16bf16_1k(a, b, c, 0, 0, 0);
#else
    floatx4 d;
    asm volatile("v_mfma_f32_16x16x16_bf16 %0, %1, %2, %3"
                 : "=v"(d) : "v"(a), "v"(b), "v"(c));
    return d;
#endif
}

#define GLD16(gp, lp)                                                        \
    __builtin_amdgcn_global_load_lds(                                        \
        (const __attribute__((address_space(1))) void*)(gp),                 \
        (__attribute__((address_space(3))) void*)(lp), 16, 0, 0)

// ---------------------------------------------------------------------------
// Prep 1: x fp32 [4096][1024] -> bf16 (straight). 1 float4 per thread.
// ---------------------------------------------------------------------------
__global__ __launch_bounds__(256) void convert_x(
    const float* __restrict__ x, unsigned short* __restrict__ xb)
{
    const int i = blockIdx.x * 256 + threadIdx.x;
    const float4 v = ((const float4*)x)[i];
    ushort4 o;
    o.x = f2bf(v.x); o.y = f2bf(v.y); o.z = f2bf(v.z); o.w = f2bf(v.w);
    ((ushort4*)xb)[i] = o;
}

// ---------------------------------------------------------------------------
// Prep 2: W fp32 [k][n] -> wt bf16 [n][k], tiled transpose. z selects Q/K/V.
// ---------------------------------------------------------------------------
__global__ __launch_bounds__(256) void transpose_w(
    const float* __restrict__ Wq, const float* __restrict__ Wk,
    const float* __restrict__ Wv, unsigned short* __restrict__ wt)
{
    const float* W = (blockIdx.z == 0) ? Wq : (blockIdx.z == 1) ? Wk : Wv;
    unsigned short* out = wt + (size_t)blockIdx.z * HID * HID;
    __shared__ float tile[32][33];
    const int tx = threadIdx.x & 31, ty = threadIdx.x >> 5;
    const int bx = blockIdx.x * 32, by = blockIdx.y * 32;
    #pragma unroll
    for (int j = 0; j < 4; ++j)
        tile[ty + j * 8][tx] = W[(size_t)(by + ty + j * 8) * HID + bx + tx];
    __syncthreads();
    #pragma unroll
    for (int j = 0; j < 4; ++j)
        out[(size_t)(bx + ty + j * 8) * HID + by + tx] = f2bf(tile[tx][ty + j * 8]);
}

// ---------------------------------------------------------------------------
// Kernel 1: fused QKV projection, bf16 MFMA, GLD16 ping-pong dbuf.
// z: 0=Q, 1=K (out [bh][s][d]) use direct scalar epilogue (d-contiguous,
// OK coalescing). z=2 (V, out [bh][d][s]) uses an LDS-bounce epilogue:
// the direct path was a 2-byte scatter at 4 KB stride (64 partial-line
// stores/wave); the bounce emits only full-128B-line dwordx4 stores.
// Shared LDS union: loop uses As/Bs dbuf (32 KB), epilogue reuses it as a
// 128x136 C tile (34.8 KB alloc; grid-bound at 3 blocks/CU regardless).
// ---------------------------------------------------------------------------
#define CTP 136   // C-tile pitch: 128 + 8 pad
__global__ __launch_bounds__(256) void qkv_mfma(
    const unsigned short* __restrict__ xb,
    const unsigned short* __restrict__ wt,
    const float* __restrict__ bq, const float* __restrict__ bk,
    const float* __restrict__ bv,
    unsigned short* __restrict__ ws_out)
{
    const int bn = blockIdx.x;   // 0..7
    const int bm = blockIdx.y;   // 0..31
    const int z  = blockIdx.z;   // 0..2
    const unsigned short* Bt = wt + (size_t)z * HID * HID;
    const float* bias = (z == 0) ? bq : (z == 1) ? bk : bv;
    unsigned short* out = ws_out + (size_t)z * (size_t)BH * SEQ * HDIM;

    const int t    = threadIdx.x;
    const int wave = t >> 6;
    const int lane = t & 63;
    const int l15  = lane & 15;
    const int quad = lane >> 4;
    const int wm   = (wave >> 1) * 64;
    const int wn   = (wave & 1) * 64;

    // union: [0,16384) = As dbuf + Bs dbuf (4x 4096 elems); epilogue C tile
    // needs 128*CTP = 17408 elems.
    __shared__ __align__(16) unsigned short smem[128 * CTP];
    #define ASB(buf) (smem + (buf) * 4096)
    #define BSB(buf) (smem + 8192 + (buf) * 4096)

    floatx4 acc[4][4];
    #pragma unroll
    for (int i = 0; i < 4; ++i)
        #pragma unroll
        for (int j = 0; j < 4; ++j)
            acc[i][j] = (floatx4){0.f, 0.f, 0.f, 0.f};

    const int lrow = lane >> 2;
    const int lcol = (lane & 3) * 8;

    #define QKV_STAGE(kt, buf)                                                  \
        do {                                                                    \
            _Pragma("unroll")                                                   \
            for (int ee = 0; ee < 2; ++ee) {                                    \
                const int e = wave * 2 + ee;                                    \
                const unsigned short* ga = xb +                                 \
                    (size_t)(bm * 128 + e * 16 + lrow) * HID + (kt) * 32 + lcol;\
                const unsigned short* gb = Bt +                                 \
                    (size_t)(bn * 128 + e * 16 + lrow) * HID + (kt) * 32 + lcol;\
                GLD16(ga, (char*)ASB(buf) + e * 1024);                          \
                GLD16(gb, (char*)BSB(buf) + e * 1024);                          \
            }                                                                   \
        } while (0)

    QKV_STAGE(0, 0);

    for (int kt = 0; kt < HID / 32; ++kt) {
        const int buf = kt & 1;
        __syncthreads();   // drains DMA for tile kt; syncs prev compute reads
        if (kt + 1 < HID / 32)
            QKV_STAGE(kt + 1, buf ^ 1);   // overlaps with compute below

        short8 af[4], bf[4];
        #pragma unroll
        for (int mt = 0; mt < 4; ++mt)
            af[mt] = *(const short8*)&ASB(buf)[(wm + mt * 16 + l15) * 32 + quad * 8];
        #pragma unroll
        for (int nt = 0; nt < 4; ++nt)
            bf[nt] = *(const short8*)&BSB(buf)[(wn + nt * 16 + l15) * 32 + quad * 8];
        #pragma unroll
        for (int mt = 0; mt < 4; ++mt)
            #pragma unroll
            for (int nt = 0; nt < 4; ++nt)
                acc[mt][nt] = __builtin_amdgcn_mfma_f32_16x16x32_bf16(
                    af[mt], bf[nt], acc[mt][nt], 0, 0, 0);
    }
    #undef QKV_STAGE

    if (z < 2) {
        #pragma unroll
        for (int nt = 0; nt < 4; ++nt) {
            const int n_g = bn * 128 + wn + nt * 16 + l15;
            const float bsv = bias[n_g];
            const int h = n_g >> 6;
            const int d = n_g & 63;
            #pragma unroll
            for (int mt = 0; mt < 4; ++mt) {
                #pragma unroll
                for (int r = 0; r < 4; ++r) {
                    const int m_g = bm * 128 + wm + mt * 16 + quad * 4 + r;
                    const int s  = m_g >> 1;
                    const int bb = m_g & 1;
                    out[((size_t)(bb * NHEAD + h) * SEQ + s) * HDIM + d] =
                        f2bf(acc[mt][nt][r] + bsv);
                }
            }
        }
    } else {
        // ---- V: LDS bounce -> coalesced [bh][d][s] stores ----
        __syncthreads();   // all frag reads from As/Bs complete before reuse
        #pragma unroll
        for (int nt = 0; nt < 4; ++nt) {
            const int n_l = wn + nt * 16 + l15;
            const float bsv = bias[bn * 128 + n_l];
            #pragma unroll
            for (int mt = 0; mt < 4; ++mt) {
                #pragma unroll
                for (int r = 0; r < 4; ++r) {
                    const int m_l = wm + mt * 16 + quad * 4 + r;
                    // m -> (s_l, bb): s interleaved with batch (BATCH==2)
                    smem[n_l * CTP + (m_l & 1) * 64 + (m_l >> 1)] =
                        f2bf(acc[mt][nt][r] + bsv);
                }
            }
        }
        __syncthreads();
        // read back: thread t owns row (n_l = t>>1, bb = t&1) = 64 s * 2B
        const int n_l = t >> 1;
        const int b2  = t & 1;
        const int n_g = bn * 128 + n_l;
        const int h   = n_g >> 6;
        const int d   = n_g & 63;
        const unsigned short* src = smem + n_l * CTP + b2 * 64;
        unsigned short* dst =
            out + ((size_t)(b2 * NHEAD + h) * HDIM + d) * SEQ + bm * 64;
        #pragma unroll
        for (int c = 0; c < 8; ++c)    // 8 x 16B = 128 B (one full line set)
            *(uint4*)(dst + c * 8) = *(const uint4*)(src + c * 8);
    }
}
#undef CTP

// ---------------------------------------------------------------------------
// Kernel 2: flash attention v15 = v11 compute body + LDS DOUBLE-BUFFER
// (one barrier per tile instead of two).
//   History: v11 (256thr, 2 barriers/tile) = 109 µs. v14 (512thr team split,
//   occupancy 33->46.5%) = 114 µs, VALUBusy FELL 56->46: more waves gave no
//   throughput -> NOT latency/TLP-bound. Remaining suspect: lockstep barrier
//   serialization — HIP emits s_waitcnt vmcnt(0) lgkmcnt(0) before every
//   s_barrier, so 64 barriers/block drain everything; the LDS
//   write->barrier->read turnaround sits serially on the critical path.
//   v15: ping-pong K/V buffers (2 x 16 KB; 4 blocks/CU at 128 KB): iteration
//   kt writes tile kt+1 into buf^1 (overlaps compute on buf), issues global
//   loads for tile kt+2 into regs, computes, ONE barrier. Barrier count
//   33 vs 64; write->read turnaround fully overlapped.
//   Ordering proof: compute(kt) reads buf written in phase A of kt-1,
//   separated by the end-of-kt-1 barrier; phase A of kt writes buf^1 which
//   was last read by compute(kt-1), also separated by that barrier.
//   Numerics identical to v11 (same op order; mask dbuf scheme kept).
//   LDS tile layout proven v9-v11: 128 B rows, XOR swizzle
//   byte = row*128 + (col ^ ((row&7)<<4)), both staging writes and reads.
// 256 threads, 4 waves x 16 q-rows, grid (32 qb, 32 heads) = 1024 blocks.
// q,kp: [bh][s][d] bf16; vt: [bh][d][s] bf16; mask: [B][1][S][S] fp32.
// ---------------------------------------------------------------------------
__global__ __launch_bounds__(256) void attn_v15(
    const unsigned short* __restrict__ q,
    const unsigned short* __restrict__ kp,
    const unsigned short* __restrict__ vt,
    const float* __restrict__ mask,
    float* __restrict__ out)
{
    const int qb   = blockIdx.x;   // 0..31 query tile (64 rows)
    const int n    = blockIdx.y;   // 0..31 flattened head
    const int t    = threadIdx.x;
    const int wave = t >> 6;
    const int lane = t & 63;
    const int l15  = lane & 15;
    const int quad = lane >> 4;
    const int bb   = n >> 4;       // batch
    const int hh   = n & 15;       // head

    // double-buffered 64x64 bf16 tiles, 128 B rows, XOR-swizzled
    __shared__ __align__(16) unsigned short Ks[2][64 * 64];
    __shared__ __align__(16) unsigned short Vs[2][64 * 64];

    // ---- Q fragments straight from global (one-time) ----
    const unsigned short* qbase = q + ((size_t)n * SEQ + qb * 64) * HDIM;
    short8 Qf[2];
    #pragma unroll
    for (int ks = 0; ks < 2; ++ks)
        Qf[ks] = *(const short8*)(qbase +
            (size_t)(wave * 16 + l15) * HDIM + ks * 32 + quad * 8);

    floatx4 Of[4];
    #pragma unroll
    for (int nt = 0; nt < 4; ++nt) Of[nt] = (floatx4){0.f, 0.f, 0.f, 0.f};
    float lst = 0.0f;

    const unsigned short* kbase = kp + (size_t)n * SEQ * HDIM;
    const unsigned short* vbase = vt + (size_t)n * HDIM * SEQ;
    const float* mrow = mask + ((size_t)bb * SEQ + qb * 64 + wave * 16 + l15) * SEQ;

    // per-thread staging addresses (two 8-bf16 chunks each for K and V)
    const int c0 = t,        r0 = c0 >> 3, o0 = (c0 & 7) * 8;
    const int c1 = t + 256,  r1 = c1 >> 3, o1 = (c1 & 7) * 8;
    // swizzled LDS byte destinations for the staging writes
    const int sw0 = r0 * 128 + ((o0 * 2) ^ ((r0 & 7) << 4));
    const int sw1 = r1 * 128 + ((o1 * 2) ^ ((r1 & 7) << 4));
    // read-side swizzle term (row & 7 == l15 & 7 for all fragment reads)
    const int rsw = (l15 & 7) << 4;

    uint4 kreg0, kreg1, vreg0, vreg1;
    #define LOADT(tl)                                                          \
        do {                                                                   \
            const unsigned short* kb_ = kbase + (size_t)((tl) * 64) * HDIM;    \
            const unsigned short* vb_ = vbase + (tl) * 64;                     \
            kreg0 = *(const uint4*)(kb_ + (size_t)r0 * HDIM + o0);             \
            kreg1 = *(const uint4*)(kb_ + (size_t)r1 * HDIM + o1);             \
            vreg0 = *(const uint4*)(vb_ + (size_t)r0 * SEQ + o0);              \
            vreg1 = *(const uint4*)(vb_ + (size_t)r1 * SEQ + o1);              \
        } while (0)

    // ---- prologue: tile 0 -> buf 0; tile 1 -> regs; mask tile 0 ----
    LOADT(0);
    *(uint4*)((char*)Ks[0] + sw0) = kreg0;
    *(uint4*)((char*)Ks[0] + sw1) = kreg1;
    *(uint4*)((char*)Vs[0] + sw0) = vreg0;
    *(uint4*)((char*)Vs[0] + sw1) = vreg1;
    LOADT(1);
    float4 mreg[4], mnext[4];
    #pragma unroll
    for (int mt = 0; mt < 4; ++mt)
        mreg[mt] = mul4(*(const float4*)(mrow + mt * 16 + quad * 4), LOG2E);
    __syncthreads();   // buf0 visible (also drains tile-1 loads; one-time)

    for (int kt = 0; kt < SEQ / 64; ++kt) {
        const int buf = kt & 1;
        char* const KsB = (char*)Ks[buf];
        char* const VsB = (char*)Vs[buf];

        if (kt + 1 < SEQ / 64) {   // phase A: regs(tile kt+1) -> buf^1
            char* const KsW = (char*)Ks[buf ^ 1];
            char* const VsW = (char*)Vs[buf ^ 1];
            *(uint4*)(KsW + sw0) = kreg0;
            *(uint4*)(KsW + sw1) = kreg1;
            *(uint4*)(VsW + sw0) = vreg0;
            *(uint4*)(VsW + sw1) = vreg1;
        }
        if (kt + 2 < SEQ / 64)     // phase B: issue loads for tile kt+2
            LOADT(kt + 2);
        if (kt + 1 < SEQ / 64) {   // mask prefetch for tile kt+1
            #pragma unroll
            for (int mt = 0; mt < 4; ++mt)
                mnext[mt] = *(const float4*)(mrow + (kt + 1) * 64 + mt * 16 + quad * 4);
        }

        // per 16-key subtile: S^T MFMA -> softmax -> in-register P -> PV
        #pragma unroll
        for (int mt = 0; mt < 4; ++mt) {
            floatx4 c = (floatx4){0.f, 0.f, 0.f, 0.f};
            #pragma unroll
            for (int ks = 0; ks < 2; ++ks) {
                short8 a = *(const short8*)(KsB + (mt * 16 + l15) * 128 +
                                            ((ks * 64 + quad * 16) ^ rsw));
                c = __builtin_amdgcn_mfma_f32_16x16x32_bf16(a, Qf[ks], c, 0, 0, 0);
            }

            const float4 mv = mreg[mt];   // already * LOG2E
            const float pv0 = exp2f(fmaf(c[0], SCALE_LOG2E, mv.x));
            const float pv1 = exp2f(fmaf(c[1], SCALE_LOG2E, mv.y));
            const float pv2 = exp2f(fmaf(c[2], SCALE_LOG2E, mv.z));
            const float pv3 = exp2f(fmaf(c[3], SCALE_LOG2E, mv.w));
            lst += (pv0 + pv1) + (pv2 + pv3);

            short4v Af;
            Af[0] = (short)f2bf(pv0);
            Af[1] = (short)f2bf(pv1);
            Af[2] = (short)f2bf(pv2);
            Af[3] = (short)f2bf(pv3);

            #pragma unroll
            for (int nt = 0; nt < 4; ++nt) {
                short4v Bf = *(const short4v*)(VsB + (nt * 16 + l15) * 128 +
                                               ((mt * 32 + quad * 8) ^ rsw));
                Of[nt] = mfma16x16x16(Af, Bf, Of[nt]);
            }
        }

        if (kt + 1 < SEQ / 64) {   // fold LOG2E (off critical path)
            #pragma unroll
            for (int mt = 0; mt < 4; ++mt) mreg[mt] = mul4(mnext[mt], LOG2E);
        }
        __syncthreads();   // ONE barrier: phase-A writes visible; buf free
    }
    #undef LOADT

    // ---- epilogue: reduce l across quads, normalize, store ----
    lst += __shfl_xor(lst, 16);
    lst += __shfl_xor(lst, 32);   // lane with l15=q now holds full row sum
    #pragma unroll
    for (int r = 0; r < 4; ++r) {
        const float lrow = __shfl(lst, quad * 4 + r);   // row q = quad*4+r
        const float inv  = 1.0f / lrow;
        const int s = qb * 64 + wave * 16 + quad * 4 + r;
        float* orow = out + ((size_t)s * BATCH + bb) * HID + hh * 64;
        #pragma unroll
        for (int nt = 0; nt < 4; ++nt)
            orow[nt * 16 + l15] = Of[nt][r] * inv;
    }
}

// ---------------------------------------------------------------------------
extern "C" void kernel_launch(void* const* d_in, const int* in_sizes, int n_in,
                              void* d_out, int out_size, void* d_ws, size_t ws_size,
                              hipStream_t stream) {
    const float* x    = (const float*)d_in[0];
    const float* mask = (const float*)d_in[1];
    const float* Wq   = (const float*)d_in[2];
    const float* bq   = (const float*)d_in[3];
    const float* Wk   = (const float*)d_in[4];
    const float* bk   = (const float*)d_in[5];
    const float* Wv   = (const float*)d_in[6];
    const float* bv   = (const float*)d_in[7];
    float* out = (float*)d_out;

    const size_t per = (size_t)BH * SEQ * HDIM;   // 4,194,304 elems (8 MB bf16)
    unsigned short* qw = (unsigned short*)d_ws;   // 8 MB
    unsigned short* kw = qw + per;                // 8 MB
    unsigned short* vw = kw + per;                // 8 MB (V transposed [bh][d][s])
    unsigned short* xb = vw + per;                // 8 MB (x bf16)
    unsigned short* wt = xb + per;                // 6 MB (3x W^T bf16)

    convert_x<<<dim3(SEQ * BATCH * HID / 4 / 256), dim3(256), 0, stream>>>(x, xb);
    transpose_w<<<dim3(32, 32, 3), dim3(256), 0, stream>>>(Wq, Wk, Wv, wt);

    qkv_mfma<<<dim3(HID / 128, SEQ * BATCH / 128, 3), dim3(256), 0, stream>>>(
        xb, wt, bq, bk, bv, qw);

    attn_v15<<<dim3(SEQ / 64, BH), dim3(256), 0, stream>>>(qw, kw, vw, mask, out);
}